// Round 2
// baseline (226.745 us; speedup 1.0000x reference)
//
#include <hip/hip_runtime.h>
#include <math.h>

#define NCH  256
#define CROP 7

typedef float v4f __attribute__((ext_vector_type(4)));

__device__ __forceinline__ float lerpf(float a, float b, float t) {
    return a + (b - a) * t;
}

// One block per ROI: 256 threads = 4 waves; each wave handles one output
// pixel across all 256 channels (64 lanes x float4), marching pix += 4
// over the 49 pixels (13 iterations).
//
// Locality rationale: all 49 pixels of an ROI bilinear-sample an ~8-14 px^2
// neighborhood of ONE feature-map level. Splitting the ROI across 13 blocks
// round-robins them over 8 XCDs, so overlapping corner rows were re-fetched
// per-XCD (L2s are private). One block per ROI turns that overlap into
// same-CU L1/L2 hits.
__global__ __launch_bounds__(256) void roialign_fpn_kernel(
    const float* __restrict__ p2, const float* __restrict__ p3,
    const float* __restrict__ p4, const float* __restrict__ p5,
    const float* __restrict__ rois, const int* __restrict__ bidx,
    float* __restrict__ out, int N)
{
    const int tid = threadIdx.x;
    const int cv  = tid & 63;            // channel quad index: c = 4*cv
    const int pl  = tid >> 6;            // wave id 0..3 (uniform per wave)
    const int n   = blockIdx.x;

    // ROI box [x1,y1,x2,y2] in image coords (uniform -> scalar loads)
    const float rx1 = rois[4*n+0];
    const float ry1 = rois[4*n+1];
    const float rx2 = rois[4*n+2];
    const float ry2 = rois[4*n+3];
    const float w = rx2 - rx1;
    const float h = ry2 - ry1;

    // level = clip(round(log2(sqrt(h*w)/224) + 4), 2, 5)
    // KEEP BIT-IDENTICAL to the verified version (level flips would blow absmax).
    const float lvlf = logf(sqrtf(h * w) / 224.0f) / logf(2.0f) + 4.0f;
    int lvl = (int)rintf(lvlf);
    lvl = lvl < 2 ? 2 : (lvl > 5 ? 5 : lvl);
    const int i = lvl - 2;               // 0..3 -> p2..p5, stride 4<<i

    const int H = 256 >> i;              // square maps
    const float* fm = (i == 0) ? p2 : (i == 1) ? p3 : (i == 2) ? p4 : p5;
    const float inv = 1.0f / (float)((4 << i) * H);  // (roi/stride)/H, exact pow2
    const float Hm1 = (float)(H - 1);

    const float ny1 = ry1 * inv, ny2 = ry2 * inv;
    const float nx1 = rx1 * inv, nx2 = rx2 * inv;

    const int b = bidx[n];
    const size_t bbase = (size_t)b * H;
    const int c = cv * 4;
    float* outn = out + (size_t)n * (CROP * CROP * NCH) + c;

    // Fused second tuple output: batch_indices as float at the flat tail.
    if (tid == 0)
        out[(size_t)N * (CROP * CROP * NCH) + n] = (float)b;

    #pragma unroll 2
    for (int pix = pl; pix < CROP * CROP; pix += 4) {
        const int jy = pix / CROP;
        const int jx = pix - jy * CROP;

        // g = j/6.0 (float division to match np bit-for-bit)
        const float gy = (float)jy / 6.0f;
        const float gx = (float)jx / 6.0f;
        const float in_y = (ny1 + (ny2 - ny1) * gy) * Hm1;
        const float in_x = (nx1 + (nx2 - nx1) * gx) * Hm1;

        const bool valid = (in_y >= 0.0f) && (in_y <= Hm1) &&
                           (in_x >= 0.0f) && (in_x <= Hm1);

        const float y0f = floorf(in_y);
        const float x0f = floorf(in_x);
        const float ly = in_y - y0f;
        const float lx = in_x - x0f;
        const int y0 = (int)fminf(fmaxf(y0f,          0.0f), Hm1);
        const int y1 = (int)fminf(fmaxf(ceilf(in_y),  0.0f), Hm1);
        const int x0 = (int)fminf(fmaxf(x0f,          0.0f), Hm1);
        const int x1 = (int)fminf(fmaxf(ceilf(in_x),  0.0f), Hm1);

        const size_t row0 = (bbase + y0) * (size_t)H;
        const size_t row1 = (bbase + y1) * (size_t)H;

        const v4f tl = *(const v4f*)(fm + (row0 + x0) * NCH + c);
        const v4f tr = *(const v4f*)(fm + (row0 + x1) * NCH + c);
        const v4f bl = *(const v4f*)(fm + (row1 + x0) * NCH + c);
        const v4f br = *(const v4f*)(fm + (row1 + x1) * NCH + c);

        v4f r;
        r.x = lerpf(lerpf(tl.x, tr.x, lx), lerpf(bl.x, br.x, lx), ly);
        r.y = lerpf(lerpf(tl.y, tr.y, lx), lerpf(bl.y, br.y, lx), ly);
        r.z = lerpf(lerpf(tl.z, tr.z, lx), lerpf(bl.z, br.z, lx), ly);
        r.w = lerpf(lerpf(tl.w, tr.w, lx), lerpf(bl.w, br.w, lx), ly);
        if (!valid) { r.x = 0.0f; r.y = 0.0f; r.z = 0.0f; r.w = 0.0f; }

        // Output has zero reuse -> nontemporal store keeps L2 for fm reads.
        __builtin_nontemporal_store(r, (v4f*)(outn + (size_t)pix * NCH));
    }
}

extern "C" void kernel_launch(void* const* d_in, const int* in_sizes, int n_in,
                              void* d_out, int out_size, void* d_ws, size_t ws_size,
                              hipStream_t stream) {
    const float* p2   = (const float*)d_in[0];
    const float* p3   = (const float*)d_in[1];
    const float* p4   = (const float*)d_in[2];
    const float* p5   = (const float*)d_in[3];
    const float* rois = (const float*)d_in[4];
    const int*   bidx = (const int*)d_in[5];
    float* out = (float*)d_out;

    const int N = in_sizes[5];           // number of ROIs

    roialign_fpn_kernel<<<dim3(N), 256, 0, stream>>>(p2, p3, p4, p5, rois, bidx,
                                                     out, N);
}